// Round 2
// baseline (1920.880 us; speedup 1.0000x reference)
//
#include <hip/hip_runtime.h>
#include <hip/hip_bf16.h>

// Multihead attention fwd: x(B,S,D) -> out(B,S,D)
// B=4 S=2048 D=1024 H=16 DK=64, RoPE on Q,K, causal softmax.
// Round 2: fp32 baseline, tuned.
//   k1-3: proj GEMM 128x128 tile, 8x8 micro (x @ W^T) + optional RoPE,
//         scatter to (B,H,S,DK). B-tile XOR-swizzled in LDS.
//   k4  : flash attention, 64x64 tiles, online softmax, static LDS.
//   k5  : out GEMM (AO @ Wo^T) -> d_out
// ws: Q,K,V,AO fp32 = 4 * 33.5 MB = 134 MB

constexpr int Bn = 4;
constexpr int Sn = 2048;
constexpr int Dm = 1024;
constexpr int Hn = 16;
constexpr int Dk = 64;
constexpr int Mtot = Bn * Sn;   // 8192

// ---------------- GEMM: out = A (M x K) @ W (N x K)^T ----------------
// MODE 0: plain row-major (M x N) output
// MODE 1: scatter to (B,H,S,DK)
// MODE 2: scatter + RoPE
// BM=BN=128, BK=16; 256 threads; 8x8 micro-tile/thread.
// LDS k-major As[BK][132] (pad 132 words = conflict-free 8-wide b128 reads
// for A via ty*8 spacing). Bs columns XOR-swizzled (word bits 2-3 ^= bits
// 5-6) so the tx*8-strided b128 reads are <=2-way (free); staging writes
// are 2-way (free).
__device__ __forceinline__ int bswz(int col) {
    return col ^ (((col >> 5) & 3) << 2);
}

template<int MODE>
__global__ __launch_bounds__(256)
void gemm128(const float* __restrict__ A, const float* __restrict__ W,
             float* __restrict__ out, const int* __restrict__ pos)
{
    __shared__ float As[16][132];
    __shared__ float Bs[16][132];

    const int tid = threadIdx.x;
    const int tx = tid & 15;        // 8 n-cols
    const int ty = tid >> 4;        // 8 m-rows
    const int m0 = blockIdx.y * 128;
    const int n0 = blockIdx.x * 128;

    const int lrow = tid >> 1;       // 0..127 tile row
    const int lk   = (tid & 1) * 8;  // 0 or 8

    const float* Aptr = A + (size_t)(m0 + lrow) * Dm + lk;
    const float* Wptr = W + (size_t)(n0 + lrow) * Dm + lk;

    const int wcol = bswz(lrow);             // swizzled store col for Bs
    const int b0c = bswz(tx * 8);            // swizzled read cols
    const int b1c = bswz(tx * 8 + 4);

    float acc[8][8] = {};

    for (int k0 = 0; k0 < Dm; k0 += 16) {
        float4 av0 = *reinterpret_cast<const float4*>(Aptr + k0);
        float4 av1 = *reinterpret_cast<const float4*>(Aptr + k0 + 4);
        float4 bv0 = *reinterpret_cast<const float4*>(Wptr + k0);
        float4 bv1 = *reinterpret_cast<const float4*>(Wptr + k0 + 4);
        __syncthreads();   // protect previous iteration's reads
        As[lk + 0][lrow] = av0.x; As[lk + 1][lrow] = av0.y;
        As[lk + 2][lrow] = av0.z; As[lk + 3][lrow] = av0.w;
        As[lk + 4][lrow] = av1.x; As[lk + 5][lrow] = av1.y;
        As[lk + 6][lrow] = av1.z; As[lk + 7][lrow] = av1.w;
        Bs[lk + 0][wcol] = bv0.x; Bs[lk + 1][wcol] = bv0.y;
        Bs[lk + 2][wcol] = bv0.z; Bs[lk + 3][wcol] = bv0.w;
        Bs[lk + 4][wcol] = bv1.x; Bs[lk + 5][wcol] = bv1.y;
        Bs[lk + 6][wcol] = bv1.z; Bs[lk + 7][wcol] = bv1.w;
        __syncthreads();
        #pragma unroll
        for (int kk = 0; kk < 16; ++kk) {
            float4 a0 = *reinterpret_cast<const float4*>(&As[kk][ty * 8]);
            float4 a1 = *reinterpret_cast<const float4*>(&As[kk][ty * 8 + 4]);
            float4 b0 = *reinterpret_cast<const float4*>(&Bs[kk][b0c]);
            float4 b1 = *reinterpret_cast<const float4*>(&Bs[kk][b1c]);
            float ar[8] = {a0.x, a0.y, a0.z, a0.w, a1.x, a1.y, a1.z, a1.w};
            float br[8] = {b0.x, b0.y, b0.z, b0.w, b1.x, b1.y, b1.z, b1.w};
            #pragma unroll
            for (int r = 0; r < 8; ++r)
                #pragma unroll
                for (int c = 0; c < 8; ++c)
                    acc[r][c] = fmaf(ar[r], br[c], acc[r][c]);
        }
    }

    if (MODE == 0) {
        (void)pos;
        #pragma unroll
        for (int r = 0; r < 8; ++r) {
            int m = m0 + ty * 8 + r;
            float* op = out + (size_t)m * Dm + n0 + tx * 8;
            *reinterpret_cast<float4*>(op) =
                make_float4(acc[r][0], acc[r][1], acc[r][2], acc[r][3]);
            *reinterpret_cast<float4*>(op + 4) =
                make_float4(acc[r][4], acc[r][5], acc[r][6], acc[r][7]);
        }
    } else {
        const int h  = (n0 >> 6) + (tx >> 3);
        const int d0 = (tx & 7) * 8;
        float invf[4];
        if (MODE == 2) {
            #pragma unroll
            for (int p = 0; p < 4; ++p)
                invf[p] = powf(10000.0f, -(float)(d0 + 2 * p) * (1.0f / 64.0f));
        }
        #pragma unroll
        for (int r = 0; r < 8; ++r) {
            int m = m0 + ty * 8 + r;
            int b = m >> 11;          // / 2048
            int s = m & (Sn - 1);
            float o[8] = {acc[r][0], acc[r][1], acc[r][2], acc[r][3],
                          acc[r][4], acc[r][5], acc[r][6], acc[r][7]};
            if (MODE == 2) {
                float pv = (float)pos[s];
                #pragma unroll
                for (int p = 0; p < 4; ++p) {
                    float sv, cv;
                    sincosf(pv * invf[p], &sv, &cv);
                    float x0 = o[2 * p], x1 = o[2 * p + 1];
                    o[2 * p]     = cv * x0 - sv * x1;
                    o[2 * p + 1] = sv * x0 + cv * x1;
                }
            }
            float* op = out + (((size_t)(b * Hn + h) * Sn + s) * Dk) + d0;
            *reinterpret_cast<float4*>(op) = make_float4(o[0], o[1], o[2], o[3]);
            *reinterpret_cast<float4*>(op + 4) = make_float4(o[4], o[5], o[6], o[7]);
        }
    }
}

// ---------------- Flash attention ----------------
// One block per (q-tile 64, head, batch). 256 threads, 4x4 micro-tiles.
// Qs/Ks stored d-major [d][q]/[d][k] (transposed on load) so the QK^T
// inner loop reads are within-row b128; Vs natural [k][d]; Ps [k][q].
// LDS 4 * 64*68*4B = 69.6 KB static (gfx950: up to 160 KB/wg).
__global__ __launch_bounds__(256)
void flash64(const float* __restrict__ Qg, const float* __restrict__ Kg,
             const float* __restrict__ Vg, float* __restrict__ Og)
{
    __shared__ float Qs[64][68];
    __shared__ float Ks[64][68];
    __shared__ float Vs[64][68];
    __shared__ float Ps[64][68];

    const int tid = threadIdx.x;
    const int tx = tid & 15;
    const int ty = tid >> 4;
    const int qt = blockIdx.x, h = blockIdx.y, b = blockIdx.z;
    const int q0 = qt * 64;
    const size_t base = (size_t)(b * Hn + h) * Sn * Dk;
    const float* Qp = Qg + base;
    const float* Kp = Kg + base;
    const float* Vp = Vg + base;

    const int lrow = tid >> 2;        // 0..63
    const int lcol = (tid & 3) * 16;  // 0,16,32,48

    // load Q tile transposed: Qs[d][q]
    #pragma unroll
    for (int j = 0; j < 4; ++j) {
        float4 v = *reinterpret_cast<const float4*>(
            Qp + (size_t)(q0 + lrow) * Dk + lcol + j * 4);
        Qs[lcol + j * 4 + 0][lrow] = v.x;
        Qs[lcol + j * 4 + 1][lrow] = v.y;
        Qs[lcol + j * 4 + 2][lrow] = v.z;
        Qs[lcol + j * 4 + 3][lrow] = v.w;
    }

    float m_r[4], l_r[4], accO[4][4] = {};
    #pragma unroll
    for (int r = 0; r < 4; ++r) { m_r[r] = -INFINITY; l_r[r] = 0.f; }

    for (int kt = 0; kt <= qt; ++kt) {
        const int k0 = kt * 64;
        __syncthreads();   // Q ready (1st iter) / prev PV done
        #pragma unroll
        for (int j = 0; j < 4; ++j) {
            float4 kv = *reinterpret_cast<const float4*>(
                Kp + (size_t)(k0 + lrow) * Dk + lcol + j * 4);
            Ks[lcol + j * 4 + 0][lrow] = kv.x;
            Ks[lcol + j * 4 + 1][lrow] = kv.y;
            Ks[lcol + j * 4 + 2][lrow] = kv.z;
            Ks[lcol + j * 4 + 3][lrow] = kv.w;
            float4 vv = *reinterpret_cast<const float4*>(
                Vp + (size_t)(k0 + lrow) * Dk + lcol + j * 4);
            *reinterpret_cast<float4*>(&Vs[lrow][lcol + j * 4]) = vv;
        }
        __syncthreads();

        // S = Q K^T (4x4 per thread)
        float s[4][4] = {};
        #pragma unroll 4
        for (int kk = 0; kk < 64; ++kk) {
            float4 a = *reinterpret_cast<const float4*>(&Qs[kk][ty * 4]);
            float4 bk = *reinterpret_cast<const float4*>(&Ks[kk][tx * 4]);
            float ar[4] = {a.x, a.y, a.z, a.w};
            float br[4] = {bk.x, bk.y, bk.z, bk.w};
            #pragma unroll
            for (int r = 0; r < 4; ++r)
                #pragma unroll
                for (int c = 0; c < 4; ++c)
                    s[r][c] = fmaf(ar[r], br[c], s[r][c]);
        }

        const bool diag = (kt == qt);
        #pragma unroll
        for (int r = 0; r < 4; ++r)
            #pragma unroll
            for (int c = 0; c < 4; ++c) {
                s[r][c] *= 0.125f;   // 1/sqrt(64)
                if (diag && (tx * 4 + c > ty * 4 + r)) s[r][c] = -INFINITY;
            }

        // online softmax per q-row (reduce across 16 tx lanes)
        #pragma unroll
        for (int r = 0; r < 4; ++r) {
            float pm = fmaxf(fmaxf(s[r][0], s[r][1]), fmaxf(s[r][2], s[r][3]));
            #pragma unroll
            for (int w = 1; w < 16; w <<= 1)
                pm = fmaxf(pm, __shfl_xor(pm, w));
            float nm = fmaxf(m_r[r], pm);
            float sc = __expf(m_r[r] - nm);
            float p[4], rs = 0.f;
            #pragma unroll
            for (int c = 0; c < 4; ++c) { p[c] = __expf(s[r][c] - nm); rs += p[c]; }
            #pragma unroll
            for (int w = 1; w < 16; w <<= 1)
                rs += __shfl_xor(rs, w);
            l_r[r] = l_r[r] * sc + rs;
            m_r[r] = nm;
            #pragma unroll
            for (int c = 0; c < 4; ++c) accO[r][c] *= sc;
            #pragma unroll
            for (int c = 0; c < 4; ++c) Ps[tx * 4 + c][ty * 4 + r] = p[c];
        }
        __syncthreads();

        // O += P V
        #pragma unroll 4
        for (int kk = 0; kk < 64; ++kk) {
            float4 pa = *reinterpret_cast<const float4*>(&Ps[kk][ty * 4]);
            float4 vb = *reinterpret_cast<const float4*>(&Vs[kk][tx * 4]);
            float pr[4] = {pa.x, pa.y, pa.z, pa.w};
            float vr[4] = {vb.x, vb.y, vb.z, vb.w};
            #pragma unroll
            for (int r = 0; r < 4; ++r)
                #pragma unroll
                for (int c = 0; c < 4; ++c)
                    accO[r][c] = fmaf(pr[r], vr[c], accO[r][c]);
        }
    }

    // epilogue: normalize, write to (B,S,D) layout
    #pragma unroll
    for (int r = 0; r < 4; ++r) {
        int q = q0 + ty * 4 + r;
        float inv = 1.0f / l_r[r];
        float4 v = make_float4(accO[r][0] * inv, accO[r][1] * inv,
                               accO[r][2] * inv, accO[r][3] * inv);
        *reinterpret_cast<float4*>(
            Og + (size_t)(b * Sn + q) * Dm + h * Dk + tx * 4) = v;
    }
}

extern "C" void kernel_launch(void* const* d_in, const int* in_sizes, int n_in,
                              void* d_out, int out_size, void* d_ws, size_t ws_size,
                              hipStream_t stream)
{
    (void)in_sizes; (void)n_in; (void)out_size; (void)ws_size;
    const float* x  = (const float*)d_in[0];
    const float* Wq = (const float*)d_in[1];
    const float* Wk = (const float*)d_in[2];
    const float* Wv = (const float*)d_in[3];
    const float* Wo = (const float*)d_in[4];
    const int*  pos = (const int*)d_in[5];
    float* out = (float*)d_out;

    const size_t perBuf = (size_t)Bn * Hn * Sn * Dk;   // 8.39M floats
    float* Qb = (float*)d_ws;
    float* Kb = Qb + perBuf;
    float* Vb = Kb + perBuf;
    float* AO = Vb + perBuf;

    dim3 blk(256);
    dim3 gg(Dm / 128, Mtot / 128);   // (8, 64)
    hipLaunchKernelGGL((gemm128<2>), gg, blk, 0, stream, x, Wq, Qb, pos);
    hipLaunchKernelGGL((gemm128<2>), gg, blk, 0, stream, x, Wk, Kb, pos);
    hipLaunchKernelGGL((gemm128<1>), gg, blk, 0, stream, x, Wv, Vb, pos);

    dim3 fg(Sn / 64, Hn, Bn);      // (32, 16, 4)
    hipLaunchKernelGGL(flash64, fg, blk, 0, stream, Qb, Kb, Vb, AO);

    hipLaunchKernelGGL((gemm128<0>), gg, blk, 0, stream, AO, Wo, out, nullptr);
}

// Round 3
// 533.786 us; speedup vs baseline: 3.5986x; 3.5986x over previous
//
#include <hip/hip_runtime.h>
#include <hip/hip_bf16.h>

// Multihead attention fwd: x(B,S,D) -> out(B,S,D)
// B=4 S=2048 D=1024 H=16 DK=64, RoPE on Q,K, causal softmax.
// Round 3: fp16 MFMA everywhere (16x16x32_f16), fp32 accumulate.
//  - GEMMs: 128x128 tile, BK=32, 4 waves, 4x4 16x16 tiles/wave.
//    LDS [128][40] f16 (pad -> conflict-free b128 reads+writes).
//  - flash: S^T = K*Q^T trick (lane owns one q-column -> scalar softmax
//    state, P stays in registers for PV). V staged transposed.
//    Matched A/B k-slot rules make results independent of the hw k-map.
// ws: Q,K,V (B,H,S,64) f32 + AO (B,S,1024) f32 = 134 MB.

typedef _Float16 half4_t __attribute__((ext_vector_type(4)));
typedef _Float16 half8_t __attribute__((ext_vector_type(8)));
typedef float    floatx4 __attribute__((ext_vector_type(4)));

constexpr int Bn = 4, Sn = 2048, Dm = 1024, Hn = 16, Dk = 64;

__device__ __forceinline__ half8_t cvt8(float4 a, float4 b) {
    half8_t h;
    h[0] = (_Float16)a.x; h[1] = (_Float16)a.y;
    h[2] = (_Float16)a.z; h[3] = (_Float16)a.w;
    h[4] = (_Float16)b.x; h[5] = (_Float16)b.y;
    h[6] = (_Float16)b.z; h[7] = (_Float16)b.w;
    return h;
}

// ---------------- GEMM: out = A (M x K) @ W (N x K)^T ----------------
// MODE 0: plain row-major f32 (M x N) output
// MODE 1: scatter to (B,H,S,DK) f32
// MODE 2: scatter + RoPE
template<int MODE>
__global__ __launch_bounds__(256)
void mfma_gemm(const float* __restrict__ A, const float* __restrict__ W,
               float* __restrict__ out, const int* __restrict__ pos)
{
    __shared__ _Float16 As[128][40];   // row stride 20 words: conflict-free
    __shared__ _Float16 Bs[128][40];

    const int tid  = threadIdx.x;
    const int w    = tid >> 6;
    const int lane = tid & 63;
    const int h    = lane >> 4;     // 0..3 (k-slot group)
    const int lid  = lane & 15;     // row of A-frag / col of B-frag
    const int wm   = (w >> 1) * 64, wn = (w & 1) * 64;
    const int m0   = blockIdx.y * 128, n0 = blockIdx.x * 128;
    const int srow = tid >> 1, skh = (tid & 1) * 16;

    const float* Ap = A + (size_t)(m0 + srow) * Dm + skh;
    const float* Wp = W + (size_t)(n0 + srow) * Dm + skh;

    floatx4 acc[4][4] = {};

    #pragma unroll 1
    for (int k0 = 0; k0 < Dm; k0 += 32) {
        float4 a0 = *(const float4*)(Ap + k0);
        float4 a1 = *(const float4*)(Ap + k0 + 4);
        float4 a2 = *(const float4*)(Ap + k0 + 8);
        float4 a3 = *(const float4*)(Ap + k0 + 12);
        float4 b0 = *(const float4*)(Wp + k0);
        float4 b1 = *(const float4*)(Wp + k0 + 4);
        float4 b2 = *(const float4*)(Wp + k0 + 8);
        float4 b3 = *(const float4*)(Wp + k0 + 12);
        __syncthreads();   // previous iteration's frag reads done
        *(half8_t*)&As[srow][skh]     = cvt8(a0, a1);
        *(half8_t*)&As[srow][skh + 8] = cvt8(a2, a3);
        *(half8_t*)&Bs[srow][skh]     = cvt8(b0, b1);
        *(half8_t*)&Bs[srow][skh + 8] = cvt8(b2, b3);
        __syncthreads();

        half8_t af[4], bf[4];
        #pragma unroll
        for (int i = 0; i < 4; ++i) {
            af[i] = *(const half8_t*)&As[wm + 16 * i + lid][8 * h];
            bf[i] = *(const half8_t*)&Bs[wn + 16 * i + lid][8 * h];
        }
        #pragma unroll
        for (int i = 0; i < 4; ++i)
            #pragma unroll
            for (int j = 0; j < 4; ++j)
                acc[i][j] = __builtin_amdgcn_mfma_f32_16x16x32_f16(
                    af[i], bf[j], acc[i][j], 0, 0, 0);
    }

    if (MODE == 0) {
        (void)pos;
        #pragma unroll
        for (int i = 0; i < 4; ++i)
            #pragma unroll
            for (int j = 0; j < 4; ++j) {
                const int n = n0 + wn + 16 * j + lid;
                #pragma unroll
                for (int r = 0; r < 4; ++r) {
                    const int m = m0 + wm + 16 * i + 4 * h + r;
                    out[(size_t)m * Dm + n] = acc[i][j][r];
                }
            }
    } else {
        #pragma unroll
        for (int j = 0; j < 4; ++j) {
            const int n = n0 + wn + 16 * j + lid;
            const int hd = n >> 6, d = n & 63;
            float invf = 0.f;
            if (MODE == 2)
                invf = __powf(10000.0f, -(float)(d & ~1) * (1.0f / 64.0f));
            #pragma unroll
            for (int i = 0; i < 4; ++i)
                #pragma unroll
                for (int r = 0; r < 4; ++r) {
                    const int m = m0 + wm + 16 * i + 4 * h + r;
                    const int bb = m >> 11, s = m & (Sn - 1);
                    float val = acc[i][j][r];
                    float o = val;
                    if (MODE == 2) {
                        float part = __shfl_xor(val, 1);
                        float ang = (float)pos[s] * invf;
                        float sv, cv;
                        __sincosf(ang, &sv, &cv);
                        o = (d & 1) ? (sv * part + cv * val)
                                    : (cv * val - sv * part);
                    }
                    out[((size_t)(bb * Hn + hd) * Sn + s) * Dk + d] = o;
                }
        }
    }
}

// ---------------- Flash attention (MFMA fp16) ----------------
// Block: (q-tile 64, head, batch), 256 thr = 4 waves; wave w owns q rows
// [q0+16w, q0+16w+16). S^T = K*Q^T so lane's softmax state is scalar
// (its q-column); P^T feeds PV straight from output regs (B-operand),
// A-operand = V^T staged transposed in LDS.
__global__ __launch_bounds__(256)
void flash_mfma(const float* __restrict__ Qg, const float* __restrict__ Kg,
                const float* __restrict__ Vg, float* __restrict__ AO)
{
    __shared__ _Float16 Ks[64][72];
    __shared__ _Float16 Qs[64][72];
    __shared__ _Float16 VT[64][72];

    const int tid  = threadIdx.x;
    const int w    = tid >> 6;
    const int lane = tid & 63;
    const int h    = lane >> 4, lid = lane & 15;
    const int qt = blockIdx.x, head = blockIdx.y, b = blockIdx.z;
    const int q0 = qt * 64;
    const size_t base = (size_t)(b * Hn + head) * Sn * Dk;

    const int srow = tid & 63, sd0 = (tid >> 6) * 16;

    {   // stage Q (once)
        const float* qp = Qg + base + (size_t)(q0 + srow) * Dk + sd0;
        float4 v0 = *(const float4*)(qp);
        float4 v1 = *(const float4*)(qp + 4);
        float4 v2 = *(const float4*)(qp + 8);
        float4 v3 = *(const float4*)(qp + 12);
        *(half8_t*)&Qs[srow][sd0]     = cvt8(v0, v1);
        *(half8_t*)&Qs[srow][sd0 + 8] = cvt8(v2, v3);
    }
    __syncthreads();
    half8_t qf[2];
    qf[0] = *(const half8_t*)&Qs[w * 16 + lid][8 * h];
    qf[1] = *(const half8_t*)&Qs[w * 16 + lid][32 + 8 * h];

    const int q_g = q0 + w * 16 + lid;
    float m_r = -1e30f, l_r = 0.f;
    floatx4 accO[4] = {};

    for (int kt = 0; kt <= qt; ++kt) {
        const int k0 = kt * 64;
        __syncthreads();   // previous tile's frag reads done
        {   // stage K (rows) and V (transposed)
            const float* kp = Kg + base + (size_t)(k0 + srow) * Dk + sd0;
            float4 k0v = *(const float4*)(kp);
            float4 k1v = *(const float4*)(kp + 4);
            float4 k2v = *(const float4*)(kp + 8);
            float4 k3v = *(const float4*)(kp + 12);
            *(half8_t*)&Ks[srow][sd0]     = cvt8(k0v, k1v);
            *(half8_t*)&Ks[srow][sd0 + 8] = cvt8(k2v, k3v);
            const float* vp = Vg + base + (size_t)(k0 + srow) * Dk + sd0;
            float4 v0v = *(const float4*)(vp);
            float4 v1v = *(const float4*)(vp + 4);
            float4 v2v = *(const float4*)(vp + 8);
            float4 v3v = *(const float4*)(vp + 12);
            const float vl[16] = {v0v.x, v0v.y, v0v.z, v0v.w,
                                  v1v.x, v1v.y, v1v.z, v1v.w,
                                  v2v.x, v2v.y, v2v.z, v2v.w,
                                  v3v.x, v3v.y, v3v.z, v3v.w};
            #pragma unroll
            for (int e = 0; e < 16; ++e)
                VT[sd0 + e][srow] = (_Float16)vl[e];
        }
        __syncthreads();

        // S^T tiles: rows k (4 x 16), cols q (16). A = K rows, B = Q^T.
        floatx4 sac[4] = {};
        #pragma unroll
        for (int t = 0; t < 4; ++t) {
            half8_t kf0 = *(const half8_t*)&Ks[16 * t + lid][8 * h];
            half8_t kf1 = *(const half8_t*)&Ks[16 * t + lid][32 + 8 * h];
            sac[t] = __builtin_amdgcn_mfma_f32_16x16x32_f16(kf0, qf[0], sac[t], 0, 0, 0);
            sac[t] = __builtin_amdgcn_mfma_f32_16x16x32_f16(kf1, qf[1], sac[t], 0, 0, 0);
        }

        // online softmax over this lane's q-column
        float pm = -1e30f;
        float svv[4][4];
        #pragma unroll
        for (int t = 0; t < 4; ++t)
            #pragma unroll
            for (int r = 0; r < 4; ++r) {
                const int kg = k0 + 16 * t + 4 * h + r;
                float x = sac[t][r] * 0.125f;     // 1/sqrt(64)
                if (kg > q_g) x = -1e30f;         // causal mask
                svv[t][r] = x;
                pm = fmaxf(pm, x);
            }
        pm = fmaxf(pm, __shfl_xor(pm, 16));
        pm = fmaxf(pm, __shfl_xor(pm, 32));
        const float nm = fmaxf(m_r, pm);
        const float sc = __expf(m_r - nm);
        float rs = 0.f;
        half8_t pf[2];
        #pragma unroll
        for (int t = 0; t < 4; ++t)
            #pragma unroll
            for (int r = 0; r < 4; ++r) {
                float p = __expf(svv[t][r] - nm);
                rs += p;
                pf[t >> 1][(t & 1) * 4 + r] = (_Float16)p;
            }
        rs += __shfl_xor(rs, 16);
        rs += __shfl_xor(rs, 32);
        l_r = l_r * sc + rs;
        m_r = nm;
        #pragma unroll
        for (int dt = 0; dt < 4; ++dt) accO[dt] *= sc;

        // O^T += V^T * P^T  (P^T direct from sac regs; matched k-slots)
        #pragma unroll
        for (int dt = 0; dt < 4; ++dt)
            #pragma unroll
            for (int kc = 0; kc < 2; ++kc) {
                half4_t v0 = *(const half4_t*)&VT[16 * dt + lid][32 * kc + 4 * h];
                half4_t v1 = *(const half4_t*)&VT[16 * dt + lid][32 * kc + 16 + 4 * h];
                half8_t vf = __builtin_shufflevector(v0, v1, 0, 1, 2, 3, 4, 5, 6, 7);
                accO[dt] = __builtin_amdgcn_mfma_f32_16x16x32_f16(
                    vf, pf[kc], accO[dt], 0, 0, 0);
            }
    }

    const float inv = 1.0f / l_r;
    #pragma unroll
    for (int dt = 0; dt < 4; ++dt)
        #pragma unroll
        for (int r = 0; r < 4; ++r) {
            const int d = 16 * dt + 4 * h + r;
            AO[((size_t)(b * Sn + q_g)) * Dm + head * Dk + d] = accO[dt][r] * inv;
        }
}

extern "C" void kernel_launch(void* const* d_in, const int* in_sizes, int n_in,
                              void* d_out, int out_size, void* d_ws, size_t ws_size,
                              hipStream_t stream)
{
    (void)in_sizes; (void)n_in; (void)out_size; (void)ws_size;
    const float* x  = (const float*)d_in[0];
    const float* Wq = (const float*)d_in[1];
    const float* Wk = (const float*)d_in[2];
    const float* Wv = (const float*)d_in[3];
    const float* Wo = (const float*)d_in[4];
    const int*  pos = (const int*)d_in[5];
    float* out = (float*)d_out;

    const size_t perBuf = (size_t)Bn * Hn * Sn * Dk;   // 8.39M floats
    float* Qb = (float*)d_ws;
    float* Kb = Qb + perBuf;
    float* Vb = Kb + perBuf;
    float* AO = Vb + perBuf;

    dim3 blk(256);
    dim3 gg(Dm / 128, (Bn * Sn) / 128);   // (8, 64)
    hipLaunchKernelGGL((mfma_gemm<2>), gg, blk, 0, stream, x, Wq, Qb, pos);
    hipLaunchKernelGGL((mfma_gemm<2>), gg, blk, 0, stream, x, Wk, Kb, pos);
    hipLaunchKernelGGL((mfma_gemm<1>), gg, blk, 0, stream, x, Wv, Vb, pos);

    dim3 fg(Sn / 64, Hn, Bn);             // (32, 16, 4)
    hipLaunchKernelGGL(flash_mfma, fg, blk, 0, stream, Qb, Kb, Vb, AO);

    hipLaunchKernelGGL((mfma_gemm<0>), gg, blk, 0, stream, AO, Wo, out, nullptr);
}

// Round 6
// 399.599 us; speedup vs baseline: 4.8070x; 1.3358x over previous
//
#include <hip/hip_runtime.h>
#include <hip/hip_bf16.h>

// Multihead attention fwd: x(B,S,D) -> out(B,S,D)
// B=4 S=2048 D=1024 H=16 DK=64, RoPE on Q,K, causal softmax.
// Round 6 (= round 4 kernel, still unbenched due to GPU timeouts):
//   k1   : cvt x, Wq, Wk, Wv, Wo -> fp16 (5 small launches)
//   k2   : fused QKV proj GEMM (grid z=3) + RoPE, fp16 out (B,H,S,DK)
//   k3   : flash attn, QBLK=128 (8 waves), dbuf LDS, reg-prefetch
//   k4   : out GEMM (AO @ Wo^T) -> fp32 d_out
// Matched A/B k-slot rules keep results independent of hw k-map.

typedef _Float16 half4_t __attribute__((ext_vector_type(4)));
typedef _Float16 half8_t __attribute__((ext_vector_type(8)));
typedef float    floatx4 __attribute__((ext_vector_type(4)));

constexpr int Bn = 4, Sn = 2048, Dm = 1024, Hn = 16, Dk = 64;
constexpr int Mtot = Bn * Sn;   // 8192

// ---------------- fp32 -> fp16 convert (n % 2048 == 0) ----------------
__global__ __launch_bounds__(256)
void cvt_f16(const float* __restrict__ in, _Float16* __restrict__ out, int n)
{
    int i = (blockIdx.x * 256 + threadIdx.x) * 8;
    if (i >= n) return;
    float4 a = *(const float4*)(in + i);
    float4 b = *(const float4*)(in + i + 4);
    half8_t h;
    h[0] = (_Float16)a.x; h[1] = (_Float16)a.y;
    h[2] = (_Float16)a.z; h[3] = (_Float16)a.w;
    h[4] = (_Float16)b.x; h[5] = (_Float16)b.y;
    h[6] = (_Float16)b.z; h[7] = (_Float16)b.w;
    *(half8_t*)(out + i) = h;
}

// ---------------- fused QKV projection ----------------
// out[z] = x @ W[z]^T scattered to (B,H,S,DK) fp16, RoPE for z<2.
// 128x128 tile, BK=64, 4 waves, 4x4 16x16x32 MFMA tiles/wave, reg-prefetch.
__global__ __launch_bounds__(256)
void proj_qkv(const _Float16* __restrict__ xh,
              const _Float16* __restrict__ Wqh,
              const _Float16* __restrict__ Wkh,
              const _Float16* __restrict__ Wvh,
              _Float16* __restrict__ outb,
              const int* __restrict__ pos)
{
    __shared__ _Float16 As[128][72];   // 144B row stride: uniform bank spread
    __shared__ _Float16 Bs[128][72];

    const int z = blockIdx.z;
    const _Float16* W = (z == 0) ? Wqh : (z == 1) ? Wkh : Wvh;
    _Float16* out = outb + (size_t)z * (size_t)Bn * Hn * Sn * Dk;

    const int tid = threadIdx.x, lane = tid & 63, w = tid >> 6;
    const int h = lane >> 4, lid = lane & 15;
    const int wm = (w >> 1) * 64, wn = (w & 1) * 64;
    const int m0 = blockIdx.y * 128, n0 = blockIdx.x * 128;
    const int sr = tid >> 1, sc = (tid & 1) * 32;

    const _Float16* Ap = xh + (size_t)(m0 + sr) * Dm + sc;
    const _Float16* Wp = W + (size_t)(n0 + sr) * Dm + sc;

    half8_t pa[4], pb[4];
    #pragma unroll
    for (int u = 0; u < 4; ++u) {
        pa[u] = *(const half8_t*)(Ap + 8 * u);
        pb[u] = *(const half8_t*)(Wp + 8 * u);
    }
    floatx4 acc[4][4] = {};

    for (int k0 = 0; k0 < Dm; k0 += 64) {
        __syncthreads();
        #pragma unroll
        for (int u = 0; u < 4; ++u) {
            *(half8_t*)&As[sr][sc + 8 * u] = pa[u];
            *(half8_t*)&Bs[sr][sc + 8 * u] = pb[u];
        }
        __syncthreads();
        if (k0 + 64 < Dm) {
            #pragma unroll
            for (int u = 0; u < 4; ++u) {
                pa[u] = *(const half8_t*)(Ap + k0 + 64 + 8 * u);
                pb[u] = *(const half8_t*)(Wp + k0 + 64 + 8 * u);
            }
        }
        #pragma unroll
        for (int kk = 0; kk < 2; ++kk) {
            half8_t af[4], bf[4];
            #pragma unroll
            for (int i = 0; i < 4; ++i) {
                af[i] = *(const half8_t*)&As[wm + 16 * i + lid][kk * 32 + 8 * h];
                bf[i] = *(const half8_t*)&Bs[wn + 16 * i + lid][kk * 32 + 8 * h];
            }
            #pragma unroll
            for (int i = 0; i < 4; ++i)
                #pragma unroll
                for (int j = 0; j < 4; ++j)
                    acc[i][j] = __builtin_amdgcn_mfma_f32_16x16x32_f16(
                        af[i], bf[j], acc[i][j], 0, 0, 0);
        }
    }

    const bool rope = (z < 2);
    #pragma unroll
    for (int j = 0; j < 4; ++j) {
        const int n = n0 + wn + 16 * j + lid;
        const int hd = n >> 6, d = n & 63;
        float invf = 0.f;
        if (rope)
            invf = __powf(10000.0f, -(float)(d & ~1) * (1.0f / 64.0f));
        #pragma unroll
        for (int i = 0; i < 4; ++i)
            #pragma unroll
            for (int r = 0; r < 4; ++r) {
                const int m = m0 + wm + 16 * i + 4 * h + r;
                const int bb = m >> 11, s = m & (Sn - 1);
                float val = acc[i][j][r];
                float o = val;
                if (rope) {
                    float part = __shfl_xor(val, 1);   // pair lane (d^1)
                    float ang = (float)pos[s] * invf;
                    float sv, cv;
                    __sincosf(ang, &sv, &cv);
                    o = (d & 1) ? (sv * part + cv * val)
                                : (cv * val - sv * part);
                }
                out[((size_t)(bb * Hn + hd) * Sn + s) * Dk + d] = (_Float16)o;
            }
    }
}

// ---------------- output GEMM: d_out = AO @ Wo^T (fp32 out) ----------------
__global__ __launch_bounds__(256)
void gemm_out(const _Float16* __restrict__ Ah, const _Float16* __restrict__ Wh,
              float* __restrict__ out)
{
    __shared__ _Float16 As[128][72];
    __shared__ _Float16 Bs[128][72];

    const int tid = threadIdx.x, lane = tid & 63, w = tid >> 6;
    const int h = lane >> 4, lid = lane & 15;
    const int wm = (w >> 1) * 64, wn = (w & 1) * 64;
    const int m0 = blockIdx.y * 128, n0 = blockIdx.x * 128;
    const int sr = tid >> 1, sc = (tid & 1) * 32;

    const _Float16* Ap = Ah + (size_t)(m0 + sr) * Dm + sc;
    const _Float16* Wp = Wh + (size_t)(n0 + sr) * Dm + sc;

    half8_t pa[4], pb[4];
    #pragma unroll
    for (int u = 0; u < 4; ++u) {
        pa[u] = *(const half8_t*)(Ap + 8 * u);
        pb[u] = *(const half8_t*)(Wp + 8 * u);
    }
    floatx4 acc[4][4] = {};

    for (int k0 = 0; k0 < Dm; k0 += 64) {
        __syncthreads();
        #pragma unroll
        for (int u = 0; u < 4; ++u) {
            *(half8_t*)&As[sr][sc + 8 * u] = pa[u];
            *(half8_t*)&Bs[sr][sc + 8 * u] = pb[u];
        }
        __syncthreads();
        if (k0 + 64 < Dm) {
            #pragma unroll
            for (int u = 0; u < 4; ++u) {
                pa[u] = *(const half8_t*)(Ap + k0 + 64 + 8 * u);
                pb[u] = *(const half8_t*)(Wp + k0 + 64 + 8 * u);
            }
        }
        #pragma unroll
        for (int kk = 0; kk < 2; ++kk) {
            half8_t af[4], bf[4];
            #pragma unroll
            for (int i = 0; i < 4; ++i) {
                af[i] = *(const half8_t*)&As[wm + 16 * i + lid][kk * 32 + 8 * h];
                bf[i] = *(const half8_t*)&Bs[wn + 16 * i + lid][kk * 32 + 8 * h];
            }
            #pragma unroll
            for (int i = 0; i < 4; ++i)
                #pragma unroll
                for (int j = 0; j < 4; ++j)
                    acc[i][j] = __builtin_amdgcn_mfma_f32_16x16x32_f16(
                        af[i], bf[j], acc[i][j], 0, 0, 0);
        }
    }

    #pragma unroll
    for (int i = 0; i < 4; ++i)
        #pragma unroll
        for (int j = 0; j < 4; ++j) {
            const int n = n0 + wn + 16 * j + lid;
            #pragma unroll
            for (int r = 0; r < 4; ++r) {
                const int m = m0 + wm + 16 * i + 4 * h + r;
                out[(size_t)m * Dm + n] = acc[i][j][r];
            }
        }
}

// ---------------- Flash attention ----------------
// Block: 128 q-rows (8 waves x 16), k-tiles of 64. 512 threads.
// S^T = K*Q^T (lane owns one q-column; scalar softmax state); P^T feeds
// PV from regs (B-op); A-op = V^T staged transposed. Double-buffered LDS,
// 1 barrier/tile, register prefetch of next K/V tile.
__global__ __launch_bounds__(512)
void flash_f16(const _Float16* __restrict__ Qg, const _Float16* __restrict__ Kg,
               const _Float16* __restrict__ Vg, _Float16* __restrict__ AO)
{
    __shared__ _Float16 Ks[2][64][72];
    __shared__ _Float16 VT[2][64][72];

    const int tid = threadIdx.x, lane = tid & 63, w = tid >> 6;
    const int h = lane >> 4, lid = lane & 15;
    const int qt = (int)gridDim.x - 1 - (int)blockIdx.x;   // heavy blocks first
    const int head = blockIdx.y, b = blockIdx.z;
    const int q0 = qt * 128;
    const size_t base = (size_t)(b * Hn + head) * Sn * Dk;

    // Q fragments straight from global (one-time)
    const int wq = q0 + 16 * w + lid;
    const half8_t qf0 = *(const half8_t*)(Qg + base + (size_t)wq * Dk + 8 * h);
    const half8_t qf1 = *(const half8_t*)(Qg + base + (size_t)wq * Dk + 32 + 8 * h);

    const int nt = 2 * qt + 2;          // k-tiles (covers k < q0+128)
    const int sr = tid >> 3, sj = tid & 7;
    const _Float16* Kp = Kg + base + (size_t)sr * Dk + 8 * sj;
    const _Float16* Vp = Vg + base + (size_t)sr * Dk + 8 * sj;

    // prologue: stage tile 0
    {
        half8_t k0v = *(const half8_t*)(Kp);
        half8_t v0v = *(const half8_t*)(Vp);
        *(half8_t*)&Ks[0][sr][8 * sj] = k0v;
        #pragma unroll
        for (int e = 0; e < 8; ++e) {          // staggered: conflict-free
            int ee = (e + sj) & 7;
            VT[0][8 * sj + ee][sr] = v0v[ee];
        }
    }
    __syncthreads();

    float m_r = -1e30f, l_r = 0.f;
    floatx4 accO[4] = {};

    for (int t = 0; t < nt; ++t) {
        const int cur = t & 1;
        half8_t kn, vn;
        const bool more = (t + 1 < nt);
        if (more) {   // issue next-tile loads (hidden under compute)
            kn = *(const half8_t*)(Kp + (size_t)(t + 1) * 64 * Dk);
            vn = *(const half8_t*)(Vp + (size_t)(t + 1) * 64 * Dk);
        }

        const int k0 = t * 64;
        const bool active = (k0 <= q0 + 16 * w + 15);   // wave has unmasked k
        if (active) {
            // S^T = K * Q^T
            floatx4 sac[4] = {};
            #pragma unroll
            for (int tt = 0; tt < 4; ++tt) {
                half8_t kf0 = *(const half8_t*)&Ks[cur][16 * tt + lid][8 * h];
                half8_t kf1 = *(const half8_t*)&Ks[cur][16 * tt + lid][32 + 8 * h];
                sac[tt] = __builtin_amdgcn_mfma_f32_16x16x32_f16(kf0, qf0, sac[tt], 0, 0, 0);
                sac[tt] = __builtin_amdgcn_mfma_f32_16x16x32_f16(kf1, qf1, sac[tt], 0, 0, 0);
            }
            // scale + causal mask
            const bool needmask = (k0 + 63 > q0 + 16 * w);
            #pragma unroll
            for (int tt = 0; tt < 4; ++tt)
                #pragma unroll
                for (int r = 0; r < 4; ++r) {
                    float x = sac[tt][r] * 0.125f;
                    if (needmask && (k0 + 16 * tt + 4 * h + r > wq)) x = -1e30f;
                    sac[tt][r] = x;
                }
            // online softmax (this lane's q-column; combine 4 h-groups)
            float pm = -1e30f;
            #pragma unroll
            for (int tt = 0; tt < 4; ++tt)
                #pragma unroll
                for (int r = 0; r < 4; ++r) pm = fmaxf(pm, sac[tt][r]);
            pm = fmaxf(pm, __shfl_xor(pm, 16));
            pm = fmaxf(pm, __shfl_xor(pm, 32));
            const float nm = fmaxf(m_r, pm);
            const float sc = __expf(m_r - nm);
            float rs = 0.f;
            half8_t pf0, pf1;
            #pragma unroll
            for (int tt = 0; tt < 4; ++tt)
                #pragma unroll
                for (int r = 0; r < 4; ++r) {
                    float p = __expf(sac[tt][r] - nm);
                    rs += p;
                    if (tt < 2) pf0[(tt & 1) * 4 + r] = (_Float16)p;
                    else        pf1[(tt & 1) * 4 + r] = (_Float16)p;
                }
            rs += __shfl_xor(rs, 16);
            rs += __shfl_xor(rs, 32);
            l_r = l_r * sc + rs;
            m_r = nm;
            #pragma unroll
            for (int dt = 0; dt < 4; ++dt) accO[dt] *= sc;
            // O^T += V^T * P^T  (matched k-slot rules)
            #pragma unroll
            for (int dt = 0; dt < 4; ++dt) {
                half4_t a0 = *(const half4_t*)&VT[cur][16 * dt + lid][4 * h];
                half4_t a1 = *(const half4_t*)&VT[cur][16 * dt + lid][16 + 4 * h];
                half8_t vf0 = __builtin_shufflevector(a0, a1, 0, 1, 2, 3, 4, 5, 6, 7);
                accO[dt] = __builtin_amdgcn_mfma_f32_16x16x32_f16(vf0, pf0, accO[dt], 0, 0, 0);
                half4_t b0 = *(const half4_t*)&VT[cur][16 * dt + lid][32 + 4 * h];
                half4_t b1 = *(const half4_t*)&VT[cur][16 * dt + lid][48 + 4 * h];
                half8_t vf1 = __builtin_shufflevector(b0, b1, 0, 1, 2, 3, 4, 5, 6, 7);
                accO[dt] = __builtin_amdgcn_mfma_f32_16x16x32_f16(vf1, pf1, accO[dt], 0, 0, 0);
            }
        }

        if (more) {   // stage next tile into the other buffer
            *(half8_t*)&Ks[cur ^ 1][sr][8 * sj] = kn;
            #pragma unroll
            for (int e = 0; e < 8; ++e) {
                int ee = (e + sj) & 7;
                VT[cur ^ 1][8 * sj + ee][sr] = vn[ee];
            }
        }
        __syncthreads();
    }

    const float inv = 1.0f / l_r;
    #pragma unroll
    for (int dt = 0; dt < 4; ++dt)
        #pragma unroll
        for (int r = 0; r < 4; ++r) {
            const int d = 16 * dt + 4 * h + r;
            AO[((size_t)(b * Sn + wq)) * Dm + head * Dk + d] =
                (_Float16)(accO[dt][r] * inv);
        }
}

extern "C" void kernel_launch(void* const* d_in, const int* in_sizes, int n_in,
                              void* d_out, int out_size, void* d_ws, size_t ws_size,
                              hipStream_t stream)
{
    (void)in_sizes; (void)n_in; (void)out_size; (void)ws_size;
    const float* x  = (const float*)d_in[0];
    const float* Wq = (const float*)d_in[1];
    const float* Wk = (const float*)d_in[2];
    const float* Wv = (const float*)d_in[3];
    const float* Wo = (const float*)d_in[4];
    const int*  pos = (const int*)d_in[5];
    float* out = (float*)d_out;

    const size_t nX = (size_t)Mtot * Dm;        // 8,388,608
    const size_t nW = (size_t)Dm * Dm;          // 1,048,576
    const size_t perBuf = (size_t)Bn * Hn * Sn * Dk;   // 8,388,608

    _Float16* xh  = (_Float16*)d_ws;
    _Float16* Wqh = xh + nX;
    _Float16* Wkh = Wqh + nW;
    _Float16* Wvh = Wkh + nW;
    _Float16* Woh = Wvh + nW;
    _Float16* Qh  = Woh + nW;       // Q,K,V contiguous
    _Float16* AOh = Qh + 3 * perBuf;

    dim3 blk(256);
    hipLaunchKernelGGL(cvt_f16, dim3((int)(nX / 2048)), blk, 0, stream, x, xh, (int)nX);
    hipLaunchKernelGGL(cvt_f16, dim3((int)(nW / 2048)), blk, 0, stream, Wq, Wqh, (int)nW);
    hipLaunchKernelGGL(cvt_f16, dim3((int)(nW / 2048)), blk, 0, stream, Wk, Wkh, (int)nW);
    hipLaunchKernelGGL(cvt_f16, dim3((int)(nW / 2048)), blk, 0, stream, Wv, Wvh, (int)nW);
    hipLaunchKernelGGL(cvt_f16, dim3((int)(nW / 2048)), blk, 0, stream, Wo, Woh, (int)nW);

    dim3 gp(Dm / 128, Mtot / 128, 3);   // (8, 64, 3)
    hipLaunchKernelGGL(proj_qkv, gp, blk, 0, stream, xh, Wqh, Wkh, Wvh, Qh, pos);

    dim3 fg(Sn / 128, Hn, Bn);          // (16, 16, 4)
    hipLaunchKernelGGL(flash_f16, fg, dim3(512), 0, stream,
                       Qh, Qh + perBuf, Qh + 2 * perBuf, AOh);

    dim3 gg(Dm / 128, Mtot / 128);      // (8, 64)
    hipLaunchKernelGGL(gemm_out, gg, blk, 0, stream, AOh, Woh, out);
}

// Round 9
// 325.185 us; speedup vs baseline: 5.9070x; 1.2288x over previous
//
#include <hip/hip_runtime.h>
#include <hip/hip_bf16.h>

// Multihead attention fwd: x(B,S,D) -> out(B,S,D)
// B=4 S=2048 D=1024 H=16 DK=64, RoPE on Q,K, causal softmax.
// Round 9 (= round 7 flash v2 + cvt_pkrtz bit_cast compile fix):
// paired causal q-tiles (uniform work), exp2-domain softmax (scale folded
// into Q), defer-rescale (THR=8), cvt_pkrtz P-pack.
// GEMM kernels unchanged from round 6 (benched OK).

typedef _Float16 half2_t __attribute__((ext_vector_type(2)));
typedef _Float16 half4_t __attribute__((ext_vector_type(4)));
typedef _Float16 half8_t __attribute__((ext_vector_type(8)));
typedef float    floatx4 __attribute__((ext_vector_type(4)));

// cvt_pkrtz returns __fp16x2; bit-cast to our _Float16x2 (same bits).
__device__ __forceinline__ half2_t cvtpk(float a, float b) {
    return __builtin_bit_cast(half2_t, __builtin_amdgcn_cvt_pkrtz(a, b));
}

constexpr int Bn = 4, Sn = 2048, Dm = 1024, Hn = 16, Dk = 64;
constexpr int Mtot = Bn * Sn;   // 8192

// ---------------- fp32 -> fp16 convert (n % 2048 == 0) ----------------
__global__ __launch_bounds__(256)
void cvt_f16(const float* __restrict__ in, _Float16* __restrict__ out, int n)
{
    int i = (blockIdx.x * 256 + threadIdx.x) * 8;
    if (i >= n) return;
    float4 a = *(const float4*)(in + i);
    float4 b = *(const float4*)(in + i + 4);
    half8_t h;
    h[0] = (_Float16)a.x; h[1] = (_Float16)a.y;
    h[2] = (_Float16)a.z; h[3] = (_Float16)a.w;
    h[4] = (_Float16)b.x; h[5] = (_Float16)b.y;
    h[6] = (_Float16)b.z; h[7] = (_Float16)b.w;
    *(half8_t*)(out + i) = h;
}

// ---------------- fused QKV projection ----------------
// out[z] = x @ W[z]^T scattered to (B,H,S,DK) fp16, RoPE for z<2.
// 128x128 tile, BK=64, 4 waves, 4x4 16x16x32 MFMA tiles/wave, reg-prefetch.
__global__ __launch_bounds__(256)
void proj_qkv(const _Float16* __restrict__ xh,
              const _Float16* __restrict__ Wqh,
              const _Float16* __restrict__ Wkh,
              const _Float16* __restrict__ Wvh,
              _Float16* __restrict__ outb,
              const int* __restrict__ pos)
{
    __shared__ _Float16 As[128][72];   // 144B row stride: uniform bank spread
    __shared__ _Float16 Bs[128][72];

    const int z = blockIdx.z;
    const _Float16* W = (z == 0) ? Wqh : (z == 1) ? Wkh : Wvh;
    _Float16* out = outb + (size_t)z * (size_t)Bn * Hn * Sn * Dk;

    const int tid = threadIdx.x, lane = tid & 63, w = tid >> 6;
    const int h = lane >> 4, lid = lane & 15;
    const int wm = (w >> 1) * 64, wn = (w & 1) * 64;
    const int m0 = blockIdx.y * 128, n0 = blockIdx.x * 128;
    const int sr = tid >> 1, sc = (tid & 1) * 32;

    const _Float16* Ap = xh + (size_t)(m0 + sr) * Dm + sc;
    const _Float16* Wp = W + (size_t)(n0 + sr) * Dm + sc;

    half8_t pa[4], pb[4];
    #pragma unroll
    for (int u = 0; u < 4; ++u) {
        pa[u] = *(const half8_t*)(Ap + 8 * u);
        pb[u] = *(const half8_t*)(Wp + 8 * u);
    }
    floatx4 acc[4][4] = {};

    for (int k0 = 0; k0 < Dm; k0 += 64) {
        __syncthreads();
        #pragma unroll
        for (int u = 0; u < 4; ++u) {
            *(half8_t*)&As[sr][sc + 8 * u] = pa[u];
            *(half8_t*)&Bs[sr][sc + 8 * u] = pb[u];
        }
        __syncthreads();
        if (k0 + 64 < Dm) {
            #pragma unroll
            for (int u = 0; u < 4; ++u) {
                pa[u] = *(const half8_t*)(Ap + k0 + 64 + 8 * u);
                pb[u] = *(const half8_t*)(Wp + k0 + 64 + 8 * u);
            }
        }
        #pragma unroll
        for (int kk = 0; kk < 2; ++kk) {
            half8_t af[4], bf[4];
            #pragma unroll
            for (int i = 0; i < 4; ++i) {
                af[i] = *(const half8_t*)&As[wm + 16 * i + lid][kk * 32 + 8 * h];
                bf[i] = *(const half8_t*)&Bs[wn + 16 * i + lid][kk * 32 + 8 * h];
            }
            #pragma unroll
            for (int i = 0; i < 4; ++i)
                #pragma unroll
                for (int j = 0; j < 4; ++j)
                    acc[i][j] = __builtin_amdgcn_mfma_f32_16x16x32_f16(
                        af[i], bf[j], acc[i][j], 0, 0, 0);
        }
    }

    const bool rope = (z < 2);
    #pragma unroll
    for (int j = 0; j < 4; ++j) {
        const int n = n0 + wn + 16 * j + lid;
        const int hd = n >> 6, d = n & 63;
        float invf = 0.f;
        if (rope)
            invf = __powf(10000.0f, -(float)(d & ~1) * (1.0f / 64.0f));
        #pragma unroll
        for (int i = 0; i < 4; ++i)
            #pragma unroll
            for (int r = 0; r < 4; ++r) {
                const int m = m0 + wm + 16 * i + 4 * h + r;
                const int bb = m >> 11, s = m & (Sn - 1);
                float val = acc[i][j][r];
                float o = val;
                if (rope) {
                    float part = __shfl_xor(val, 1);   // pair lane (d^1)
                    float ang = (float)pos[s] * invf;
                    float sv, cv;
                    __sincosf(ang, &sv, &cv);
                    o = (d & 1) ? (sv * part + cv * val)
                                : (cv * val - sv * part);
                }
                out[((size_t)(bb * Hn + hd) * Sn + s) * Dk + d] = (_Float16)o;
            }
    }
}

// ---------------- output GEMM: d_out = AO @ Wo^T (fp32 out) ----------------
__global__ __launch_bounds__(256)
void gemm_out(const _Float16* __restrict__ Ah, const _Float16* __restrict__ Wh,
              float* __restrict__ out)
{
    __shared__ _Float16 As[128][72];
    __shared__ _Float16 Bs[128][72];

    const int tid = threadIdx.x, lane = tid & 63, w = tid >> 6;
    const int h = lane >> 4, lid = lane & 15;
    const int wm = (w >> 1) * 64, wn = (w & 1) * 64;
    const int m0 = blockIdx.y * 128, n0 = blockIdx.x * 128;
    const int sr = tid >> 1, sc = (tid & 1) * 32;

    const _Float16* Ap = Ah + (size_t)(m0 + sr) * Dm + sc;
    const _Float16* Wp = Wh + (size_t)(n0 + sr) * Dm + sc;

    half8_t pa[4], pb[4];
    #pragma unroll
    for (int u = 0; u < 4; ++u) {
        pa[u] = *(const half8_t*)(Ap + 8 * u);
        pb[u] = *(const half8_t*)(Wp + 8 * u);
    }
    floatx4 acc[4][4] = {};

    for (int k0 = 0; k0 < Dm; k0 += 64) {
        __syncthreads();
        #pragma unroll
        for (int u = 0; u < 4; ++u) {
            *(half8_t*)&As[sr][sc + 8 * u] = pa[u];
            *(half8_t*)&Bs[sr][sc + 8 * u] = pb[u];
        }
        __syncthreads();
        if (k0 + 64 < Dm) {
            #pragma unroll
            for (int u = 0; u < 4; ++u) {
                pa[u] = *(const half8_t*)(Ap + k0 + 64 + 8 * u);
                pb[u] = *(const half8_t*)(Wp + k0 + 64 + 8 * u);
            }
        }
        #pragma unroll
        for (int kk = 0; kk < 2; ++kk) {
            half8_t af[4], bf[4];
            #pragma unroll
            for (int i = 0; i < 4; ++i) {
                af[i] = *(const half8_t*)&As[wm + 16 * i + lid][kk * 32 + 8 * h];
                bf[i] = *(const half8_t*)&Bs[wn + 16 * i + lid][kk * 32 + 8 * h];
            }
            #pragma unroll
            for (int i = 0; i < 4; ++i)
                #pragma unroll
                for (int j = 0; j < 4; ++j)
                    acc[i][j] = __builtin_amdgcn_mfma_f32_16x16x32_f16(
                        af[i], bf[j], acc[i][j], 0, 0, 0);
        }
    }

    #pragma unroll
    for (int i = 0; i < 4; ++i)
        #pragma unroll
        for (int j = 0; j < 4; ++j) {
            const int n = n0 + wn + 16 * j + lid;
            #pragma unroll
            for (int r = 0; r < 4; ++r) {
                const int m = m0 + wm + 16 * i + 4 * h + r;
                out[(size_t)m * Dm + n] = acc[i][j][r];
            }
        }
}

// ---------------- Flash attention v2 ----------------
// Grid (8, H, B): block p handles q-tiles {p, 15-p} (128 rows each) ->
// uniform 34 k-tile-units per block, 512 blocks = 2/CU, no causal tail.
// Per q-tile: 8 waves x 16 q-rows; S^T = K*Q^T (lane owns one q-column;
// scalar softmax state in exp2 domain — 0.125*log2e folded into Q frags).
// Defer-rescale (THR=8): skip accO rescale unless max grew >8 (P<=2^8 ok
// in fp16). P packed via cvt_pkrtz, fed to PV straight from regs.
// Double-buffered LDS, 1 barrier/tile, register prefetch of next K/V.
__global__ __launch_bounds__(512)
void flash_f16(const _Float16* __restrict__ Qg, const _Float16* __restrict__ Kg,
               const _Float16* __restrict__ Vg, _Float16* __restrict__ AO)
{
    __shared__ _Float16 Ks[2][64][72];
    __shared__ _Float16 VT[2][64][72];

    const int tid = threadIdx.x, lane = tid & 63, w = tid >> 6;
    const int h = lane >> 4, lid = lane & 15;
    const int pr = blockIdx.x;          // 0..7 pair index
    const int head = blockIdx.y, b = blockIdx.z;
    const size_t base = (size_t)(b * Hn + head) * Sn * Dk;

    const int sr = tid >> 3, sj = tid & 7;
    const _Float16* Kp = Kg + base + (size_t)sr * Dk + 8 * sj;
    const _Float16* Vp = Vg + base + (size_t)sr * Dk + 8 * sj;

    const _Float16 qsc = (_Float16)0.18033688f;   // 0.125 * log2(e)

    #pragma unroll 1
    for (int seg = 0; seg < 2; ++seg) {
        const int qt = (seg == 0) ? pr : (15 - pr);
        const int q0 = qt * 128;
        const int wq = q0 + 16 * w + lid;

        // Q fragments from global, pre-scaled into exp2 domain
        half8_t qf0 = *(const half8_t*)(Qg + base + (size_t)wq * Dk + 8 * h);
        half8_t qf1 = *(const half8_t*)(Qg + base + (size_t)wq * Dk + 32 + 8 * h);
        qf0 *= qsc;
        qf1 *= qsc;

        const int nt = 2 * qt + 2;      // k-tiles for this q-tile

        // prologue: stage k-tile 0 into buf 0
        {
            half8_t k0v = *(const half8_t*)(Kp);
            half8_t v0v = *(const half8_t*)(Vp);
            // loop-end barrier of previous segment already protects buf0
            *(half8_t*)&Ks[0][sr][8 * sj] = k0v;
            #pragma unroll
            for (int e = 0; e < 8; ++e) {      // staggered: conflict-free
                int ee = (e + sj) & 7;
                VT[0][8 * sj + ee][sr] = v0v[ee];
            }
        }
        __syncthreads();

        float m_r = -1e30f, l_r = 0.f;
        floatx4 accO[4] = {};

        for (int t = 0; t < nt; ++t) {
            const int cur = t & 1;
            half8_t kn, vn;
            const bool more = (t + 1 < nt);
            if (more) {   // issue next-tile loads (hidden under compute)
                kn = *(const half8_t*)(Kp + (size_t)(t + 1) * 64 * Dk);
                vn = *(const half8_t*)(Vp + (size_t)(t + 1) * 64 * Dk);
            }

            const int k0 = t * 64;
            const bool active = (k0 <= q0 + 16 * w + 15);
            if (active) {
                // S^T = K * (scaled Q)^T  — already in exp2 domain
                floatx4 sac[4] = {};
                #pragma unroll
                for (int tt = 0; tt < 4; ++tt) {
                    half8_t kf0 = *(const half8_t*)&Ks[cur][16 * tt + lid][8 * h];
                    half8_t kf1 = *(const half8_t*)&Ks[cur][16 * tt + lid][32 + 8 * h];
                    sac[tt] = __builtin_amdgcn_mfma_f32_16x16x32_f16(kf0, qf0, sac[tt], 0, 0, 0);
                    sac[tt] = __builtin_amdgcn_mfma_f32_16x16x32_f16(kf1, qf1, sac[tt], 0, 0, 0);
                }
                // causal mask (only tiles straddling the diagonal)
                if (k0 + 63 > q0 + 16 * w) {
                    #pragma unroll
                    for (int tt = 0; tt < 4; ++tt)
                        #pragma unroll
                        for (int r = 0; r < 4; ++r)
                            if (k0 + 16 * tt + 4 * h + r > wq) sac[tt][r] = -1e30f;
                }
                // online softmax, exp2 domain, defer-rescale
                float pm = -1e30f;
                #pragma unroll
                for (int tt = 0; tt < 4; ++tt)
                    #pragma unroll
                    for (int r = 0; r < 4; ++r) pm = fmaxf(pm, sac[tt][r]);
                pm = fmaxf(pm, __shfl_xor(pm, 16));
                pm = fmaxf(pm, __shfl_xor(pm, 32));
                if (!__all(pm - m_r <= 8.0f)) {
                    const float nm = fmaxf(m_r, pm);
                    const float sc = exp2f(m_r - nm);
                    l_r *= sc;
                    #pragma unroll
                    for (int dt = 0; dt < 4; ++dt) accO[dt] *= sc;
                    m_r = nm;
                }
                float pv[16], rs = 0.f;
                #pragma unroll
                for (int tt = 0; tt < 4; ++tt)
                    #pragma unroll
                    for (int r = 0; r < 4; ++r) {
                        float p = exp2f(sac[tt][r] - m_r);
                        rs += p;
                        pv[4 * tt + r] = p;
                    }
                rs += __shfl_xor(rs, 16);
                rs += __shfl_xor(rs, 32);
                l_r += rs;
                half2_t c0 = cvtpk(pv[0], pv[1]);
                half2_t c1 = cvtpk(pv[2], pv[3]);
                half2_t c2 = cvtpk(pv[4], pv[5]);
                half2_t c3 = cvtpk(pv[6], pv[7]);
                half2_t c4 = cvtpk(pv[8], pv[9]);
                half2_t c5 = cvtpk(pv[10], pv[11]);
                half2_t c6 = cvtpk(pv[12], pv[13]);
                half2_t c7 = cvtpk(pv[14], pv[15]);
                half4_t l0 = __builtin_shufflevector(c0, c1, 0, 1, 2, 3);
                half4_t l1 = __builtin_shufflevector(c2, c3, 0, 1, 2, 3);
                half4_t l2 = __builtin_shufflevector(c4, c5, 0, 1, 2, 3);
                half4_t l3 = __builtin_shufflevector(c6, c7, 0, 1, 2, 3);
                half8_t pf0 = __builtin_shufflevector(l0, l1, 0, 1, 2, 3, 4, 5, 6, 7);
                half8_t pf1 = __builtin_shufflevector(l2, l3, 0, 1, 2, 3, 4, 5, 6, 7);
                // O^T += V^T * P^T  (matched k-slot rules)
                #pragma unroll
                for (int dt = 0; dt < 4; ++dt) {
                    half4_t a0 = *(const half4_t*)&VT[cur][16 * dt + lid][4 * h];
                    half4_t a1 = *(const half4_t*)&VT[cur][16 * dt + lid][16 + 4 * h];
                    half8_t vf0 = __builtin_shufflevector(a0, a1, 0, 1, 2, 3, 4, 5, 6, 7);
                    accO[dt] = __builtin_amdgcn_mfma_f32_16x16x32_f16(vf0, pf0, accO[dt], 0, 0, 0);
                    half4_t b0 = *(const half4_t*)&VT[cur][16 * dt + lid][32 + 4 * h];
                    half4_t b1 = *(const half4_t*)&VT[cur][16 * dt + lid][48 + 4 * h];
                    half8_t vf1 = __builtin_shufflevector(b0, b1, 0, 1, 2, 3, 4, 5, 6, 7);
                    accO[dt] = __builtin_amdgcn_mfma_f32_16x16x32_f16(vf1, pf1, accO[dt], 0, 0, 0);
                }
            }

            if (more) {   // stage next tile into the other buffer
                *(half8_t*)&Ks[cur ^ 1][sr][8 * sj] = kn;
                #pragma unroll
                for (int e = 0; e < 8; ++e) {
                    int ee = (e + sj) & 7;
                    VT[cur ^ 1][8 * sj + ee][sr] = vn[ee];
                }
            }
            __syncthreads();
        }

        const float inv = 1.0f / l_r;
        #pragma unroll
        for (int dt = 0; dt < 4; ++dt)
            #pragma unroll
            for (int r = 0; r < 4; ++r) {
                const int d = 16 * dt + 4 * h + r;
                AO[((size_t)(b * Sn + wq)) * Dm + head * Dk + d] =
                    (_Float16)(accO[dt][r] * inv);
            }
    }
}

extern "C" void kernel_launch(void* const* d_in, const int* in_sizes, int n_in,
                              void* d_out, int out_size, void* d_ws, size_t ws_size,
                              hipStream_t stream)
{
    (void)in_sizes; (void)n_in; (void)out_size; (void)ws_size;
    const float* x  = (const float*)d_in[0];
    const float* Wq = (const float*)d_in[1];
    const float* Wk = (const float*)d_in[2];
    const float* Wv = (const float*)d_in[3];
    const float* Wo = (const float*)d_in[4];
    const int*  pos = (const int*)d_in[5];
    float* out = (float*)d_out;

    const size_t nX = (size_t)Mtot * Dm;        // 8,388,608
    const size_t nW = (size_t)Dm * Dm;          // 1,048,576
    const size_t perBuf = (size_t)Bn * Hn * Sn * Dk;   // 8,388,608

    _Float16* xh  = (_Float16*)d_ws;
    _Float16* Wqh = xh + nX;
    _Float16* Wkh = Wqh + nW;
    _Float16* Wvh = Wkh + nW;
    _Float16* Woh = Wvh + nW;
    _Float16* Qh  = Woh + nW;       // Q,K,V contiguous
    _Float16* AOh = Qh + 3 * perBuf;

    dim3 blk(256);
    hipLaunchKernelGGL(cvt_f16, dim3((int)(nX / 2048)), blk, 0, stream, x, xh, (int)nX);
    hipLaunchKernelGGL(cvt_f16, dim3((int)(nW / 2048)), blk, 0, stream, Wq, Wqh, (int)nW);
    hipLaunchKernelGGL(cvt_f16, dim3((int)(nW / 2048)), blk, 0, stream, Wk, Wkh, (int)nW);
    hipLaunchKernelGGL(cvt_f16, dim3((int)(nW / 2048)), blk, 0, stream, Wv, Wvh, (int)nW);
    hipLaunchKernelGGL(cvt_f16, dim3((int)(nW / 2048)), blk, 0, stream, Wo, Woh, (int)nW);

    dim3 gp(Dm / 128, Mtot / 128, 3);   // (8, 64, 3)
    hipLaunchKernelGGL(proj_qkv, gp, blk, 0, stream, xh, Wqh, Wkh, Wvh, Qh, pos);

    dim3 fg(Sn / 256, Hn, Bn);          // (8, 16, 4) — paired q-tiles
    hipLaunchKernelGGL(flash_f16, fg, dim3(512), 0, stream,
                       Qh, Qh + perBuf, Qh + 2 * perBuf, AOh);

    dim3 gg(Dm / 128, Mtot / 128);      // (8, 64)
    hipLaunchKernelGGL(gemm_out, gg, blk, 0, stream, AOh, Woh, out);
}